// Round 2
// baseline (947.274 us; speedup 1.0000x reference)
//
#include <hip/hip_runtime.h>
#include <hip/hip_bf16.h>

// Problem constants (match reference)
#define N_UE 100000
#define N_AP 10000
#define N_E  1600000
#define DD   64
#define HH   128

typedef float f32x4 __attribute__((ext_vector_type(4)));
typedef short s8b   __attribute__((ext_vector_type(8)));
typedef short s4b   __attribute__((ext_vector_type(4)));

static __device__ __forceinline__ unsigned short f2bf(float x) {
  union { float f; unsigned int u; } v; v.f = x;
  unsigned int r = v.u + 0x7fffu + ((v.u >> 16) & 1u);  // RTN-even
  return (unsigned short)(r >> 16);
}

// K0: WTg[col][k] = bf16(W1a[k][col]) for full K=128 (B operand, [n][k]);
//     zero histogram counters and aggW accumulator.
__global__ void apk0_prep(const float* __restrict__ W1a, short* __restrict__ WTg,
                          int* __restrict__ counts, float* __restrict__ aggW) {
  int i = blockIdx.x * 256 + threadIdx.x;
  int n = gridDim.x * 256;
  for (int x = i; x < 128 * 128; x += n) {
    int col = x >> 7, k = x & 127;
    WTg[x] = (short)f2bf(W1a[k * 128 + col]);   // WTg[col*128 + k]
  }
  for (int x = i; x < N_AP; x += n) counts[x] = 0;
  for (int x = i; x < N_AP * 128 / 4; x += n)
    ((float4*)aggW)[x] = make_float4(0.f, 0.f, 0.f, 0.f);
}

// K2: histogram of dst
__global__ void apk2_hist(const int* __restrict__ dst, int* __restrict__ counts) {
  int i = blockIdx.x * blockDim.x + threadIdx.x;
  int stride = gridDim.x * blockDim.x;
  for (; i < N_E; i += stride) atomicAdd(&counts[dst[i]], 1);
}

// K3: exclusive scan of counts -> offsets[10001]; cursor = offsets copy
__global__ __launch_bounds__(256) void apk3_scan(const int* __restrict__ counts,
                                                 int* __restrict__ offsets,
                                                 int* __restrict__ cursor) {
  __shared__ int p[256];
  int t = threadIdx.x;
  const int CH = 40;  // 256*40 >= 10000
  int start = t * CH, end = min(start + CH, N_AP);
  int s = 0;
  for (int i = start; i < end; i++) s += counts[i];
  p[t] = s;
  __syncthreads();
  for (int d = 1; d < 256; d <<= 1) {
    int v = p[t] + ((t >= d) ? p[t - d] : 0);
    __syncthreads();
    p[t] = v;
    __syncthreads();
  }
  int base = (t == 0) ? 0 : p[t - 1];
  for (int i = start; i < end; i++) {
    offsets[i] = base;
    cursor[i] = base;
    base += counts[i];
  }
  if (t == 255) offsets[N_AP] = base;  // == N_E
}

// K4: scatter packed (edge_id, src, dst) into dst-sorted order, one int4/edge
__global__ void apk4_scatter(const int* __restrict__ dst, const int* __restrict__ src,
                             int* __restrict__ cursor, int4* __restrict__ triple) {
  int i = blockIdx.x * blockDim.x + threadIdx.x;
  int stride = gridDim.x * blockDim.x;
  for (; i < N_E; i += stride) {
    int d = dst[i];
    int pos = atomicAdd(&cursor[d], 1);
    triple[pos] = make_int4(i, src[i], d, 0);
  }
}

// K5: fixed 128-edge tiles over the dst-sorted edge list.
// A row p = [edge_hid[e_p] | ue_hid[src_p]] (bf16, K=128); B = W1a^T (LDS).
// C = A@W1a; t = relu(C + b1a); segment-reduce rows by dst (sorted) with
// register run-accumulators, flush via fp32 atomics at AP boundaries.
__global__ __launch_bounds__(256, 2) void apk5_edges(
    const float* __restrict__ edge_hid, const float* __restrict__ ue_hid,
    const short* __restrict__ WTg, const float* __restrict__ b1a,
    const int4* __restrict__ triple, float* __restrict__ aggW) {
  __shared__ short WT[128][140];   // B operand [n][k], pitch 140 (2-way max)
  __shared__ short A[128][140];    // A operand [edge][k]
  __shared__ int eids[128];
  __shared__ int usrc[128];
  __shared__ int segs[128];
  int t = threadIdx.x, blk = blockIdx.x;
  int wave = t >> 6, lane = t & 63, quad = lane >> 4, l16 = lane & 15;

  if (t < 128) {
    int4 tr = triple[(size_t)blk * 128 + t];
    eids[t] = tr.x; usrc[t] = tr.y; segs[t] = tr.z;
  }
  // stage WT: 128x128 shorts = 2048 s8b; 256 thr -> 8 each
  for (int i = t; i < 2048; i += 256) {
    int col = i >> 4, seg16 = i & 15;
    *(s8b*)&WT[col][seg16 * 8] = ((const s8b*)WTg)[i];
  }
  __syncthreads();

  // gather A: 2 threads per row; h=0 -> edge half (k 0..63), h=1 -> ue half
  {
    int r = t >> 1, h = t & 1;
    const float* srow = h ? (ue_hid + (size_t)usrc[r] * 64)
                          : (edge_hid + (size_t)eids[r] * 64);
    int kb = h * 64;
    for (int cc = 0; cc < 8; cc++) {
      float4 v = ((const float4*)srow)[cc * 2];
      float4 w = ((const float4*)srow)[cc * 2 + 1];
      s8b p;
      p[0] = (short)f2bf(v.x); p[1] = (short)f2bf(v.y);
      p[2] = (short)f2bf(v.z); p[3] = (short)f2bf(v.w);
      p[4] = (short)f2bf(w.x); p[5] = (short)f2bf(w.y);
      p[6] = (short)f2bf(w.z); p[7] = (short)f2bf(w.w);
      *(s8b*)&A[r][kb + cc * 8] = p;
    }
  }
  __syncthreads();

  // B fragments: wave owns cols [wave*32, wave*32+32)
  s8b bf[2][4];
  for (int ct = 0; ct < 2; ct++)
    for (int ks = 0; ks < 4; ks++)
      bf[ct][ks] = *(const s8b*)&WT[wave * 32 + ct * 16 + l16][ks * 32 + quad * 8];
  float bias0 = b1a[wave * 32 + l16];
  float bias1 = b1a[wave * 32 + 16 + l16];

  int runseg = segs[0];
  float run0 = 0.f, run1 = 0.f;
  for (int rt = 0; rt < 8; rt++) {
    s8b a0 = *(const s8b*)&A[rt * 16 + l16][quad * 8];
    s8b a1 = *(const s8b*)&A[rt * 16 + l16][32 + quad * 8];
    s8b a2 = *(const s8b*)&A[rt * 16 + l16][64 + quad * 8];
    s8b a3 = *(const s8b*)&A[rt * 16 + l16][96 + quad * 8];
    f32x4 c0 = {0.f, 0.f, 0.f, 0.f}, c1 = {0.f, 0.f, 0.f, 0.f};
    c0 = __builtin_amdgcn_mfma_f32_16x16x32_bf16(a0, bf[0][0], c0, 0, 0, 0);
    c0 = __builtin_amdgcn_mfma_f32_16x16x32_bf16(a1, bf[0][1], c0, 0, 0, 0);
    c0 = __builtin_amdgcn_mfma_f32_16x16x32_bf16(a2, bf[0][2], c0, 0, 0, 0);
    c0 = __builtin_amdgcn_mfma_f32_16x16x32_bf16(a3, bf[0][3], c0, 0, 0, 0);
    c1 = __builtin_amdgcn_mfma_f32_16x16x32_bf16(a0, bf[1][0], c1, 0, 0, 0);
    c1 = __builtin_amdgcn_mfma_f32_16x16x32_bf16(a1, bf[1][1], c1, 0, 0, 0);
    c1 = __builtin_amdgcn_mfma_f32_16x16x32_bf16(a2, bf[1][2], c1, 0, 0, 0);
    c1 = __builtin_amdgcn_mfma_f32_16x16x32_bf16(a3, bf[1][3], c1, 0, 0, 0);
    int sj[4]; float t0[4], t1[4];
    for (int j = 0; j < 4; j++) {
      int gr = rt * 16 + quad * 4 + j;
      sj[j] = segs[gr];
      t0[j] = fmaxf(c0[j] + bias0, 0.f);
      t1[j] = fmaxf(c1[j] + bias1, 0.f);
    }
    int s0 = segs[rt * 16], s1 = segs[rt * 16 + 15];
    for (int s = s0; s <= s1; s++) {
      float v0 = 0.f, v1 = 0.f;
      for (int j = 0; j < 4; j++)
        if (sj[j] == s) { v0 += t0[j]; v1 += t1[j]; }
      v0 += __shfl_xor(v0, 16); v0 += __shfl_xor(v0, 32);
      v1 += __shfl_xor(v1, 16); v1 += __shfl_xor(v1, 32);
      if (s == runseg) { run0 += v0; run1 += v1; }
      else {
        if (quad == 0) {
          atomicAdd(&aggW[(size_t)runseg * 128 + wave * 32 + l16], run0);
          atomicAdd(&aggW[(size_t)runseg * 128 + wave * 32 + 16 + l16], run1);
        }
        runseg = s; run0 = v0; run1 = v1;
      }
    }
  }
  if (quad == 0) {
    atomicAdd(&aggW[(size_t)runseg * 128 + wave * 32 + l16], run0);
    atomicAdd(&aggW[(size_t)runseg * 128 + wave * 32 + 16 + l16], run1);
  }
}

// K6: per 16 APs: Y = aggW@W1b + cnt*b1b;  T = relu([ap_hid,Y]@W2a + b2a);
//     out = T@W2b + b2b.  All fp32, weights staged through a 32KB LDS buffer.
__global__ __launch_bounds__(256) void apk6_mlp2(
    const float* __restrict__ ap_hid, const float* __restrict__ W1b,
    const float* __restrict__ b1b, const float* __restrict__ W2a,
    const float* __restrict__ b2a, const float* __restrict__ W2b,
    const float* __restrict__ b2b, const float* __restrict__ aggW,
    const int* __restrict__ offsets, float* __restrict__ out) {
  __shared__ float wbuf[64 * 128];   // 32KB weight tile
  __shared__ float zrows[16 * 128];  // agg rows, later reused as T
  __shared__ float yrows[16 * 128];
  __shared__ float arows[16 * 64];
  __shared__ float cbuf[16];
  int t = threadIdx.x;
  int apb = blockIdx.x * 16;
  for (int i = t; i < 16 * 128 / 4; i += 256)
    ((float4*)zrows)[i] = ((const float4*)(aggW + (size_t)apb * 128))[i];
  for (int i = t; i < 16 * 64 / 4; i += 256)
    ((float4*)arows)[i] = ((const float4*)(ap_hid + (size_t)apb * 64))[i];
  if (t < 16) cbuf[t] = (float)(offsets[apb + t + 1] - offsets[apb + t]);
  int j = t & 127, half = t >> 7;
  // ---- phase 1: Y = agg @ W1b + cnt*b1b
  {
    float bb = b1b[j];
    __syncthreads();
    float acc[8];
    for (int r = 0; r < 8; r++) acc[r] = cbuf[half * 8 + r] * bb;
    for (int p = 0; p < 2; p++) {
      __syncthreads();
      for (int i = t; i < 64 * 128 / 4; i += 256)
        ((float4*)wbuf)[i] = ((const float4*)(W1b + p * 64 * 128))[i];
      __syncthreads();
      for (int k = 0; k < 64; k++) {
        float w = wbuf[k * 128 + j];
        for (int r = 0; r < 8; r++)
          acc[r] += zrows[(half * 8 + r) * 128 + (p * 64 + k)] * w;
      }
    }
    for (int r = 0; r < 8; r++) yrows[(half * 8 + r) * 128 + j] = acc[r];
  }
  // ---- phase 2: T = relu([ap, Y] @ W2a + b2a), stored into zrows
  {
    float acc2[8];
    float bb = b2a[j];
    for (int r = 0; r < 8; r++) acc2[r] = bb;
    __syncthreads();
    for (int i = t; i < 64 * 128 / 4; i += 256)
      ((float4*)wbuf)[i] = ((const float4*)W2a)[i];
    __syncthreads();
    for (int k = 0; k < 64; k++) {
      float w = wbuf[k * 128 + j];
      for (int r = 0; r < 8; r++) acc2[r] += arows[(half * 8 + r) * 64 + k] * w;
    }
    for (int p = 0; p < 2; p++) {
      __syncthreads();
      for (int i = t; i < 64 * 128 / 4; i += 256)
        ((float4*)wbuf)[i] = ((const float4*)(W2a + (64 + p * 64) * 128))[i];
      __syncthreads();
      for (int k = 0; k < 64; k++) {
        float w = wbuf[k * 128 + j];
        for (int r = 0; r < 8; r++)
          acc2[r] += yrows[(half * 8 + r) * 128 + (p * 64 + k)] * w;
      }
    }
    __syncthreads();
    for (int r = 0; r < 8; r++)
      zrows[(half * 8 + r) * 128 + j] = fmaxf(acc2[r], 0.f);
  }
  // ---- phase 3: out = T @ W2b + b2b
  {
    __syncthreads();
    for (int i = t; i < 128 * 64 / 4; i += 256)
      ((float4*)wbuf)[i] = ((const float4*)W2b)[i];
    __syncthreads();
    int i2 = t & 63, q = t >> 6;
    float acc3[4];
    float bb = b2b[i2];
    for (int r = 0; r < 4; r++) acc3[r] = bb;
    for (int k = 0; k < 128; k++) {
      float w = wbuf[k * 64 + i2];
      for (int r = 0; r < 4; r++) acc3[r] += zrows[(q * 4 + r) * 128 + k] * w;
    }
    for (int r = 0; r < 4; r++)
      out[(size_t)(apb + q * 4 + r) * 64 + i2] = acc3[r];
  }
}

extern "C" void kernel_launch(void* const* d_in, const int* in_sizes, int n_in,
                              void* d_out, int out_size, void* d_ws, size_t ws_size,
                              hipStream_t stream) {
  const float* ue_hid   = (const float*)d_in[0];
  const float* ap_hid   = (const float*)d_in[1];
  const float* edge_hid = (const float*)d_in[2];
  const int*   src      = (const int*)d_in[3];
  const int*   dst      = (const int*)d_in[4];
  const float* W1a      = (const float*)d_in[5];
  const float* b1a      = (const float*)d_in[6];
  const float* W1b      = (const float*)d_in[7];
  const float* b1b      = (const float*)d_in[8];
  const float* W2a      = (const float*)d_in[9];
  const float* b2a      = (const float*)d_in[10];
  const float* W2b      = (const float*)d_in[11];
  const float* b2b      = (const float*)d_in[12];
  float* out = (float*)d_out;

  unsigned char* ws = (unsigned char*)d_ws;
  short* WTg    = (short*)(ws);                  //     32,768 B
  int* counts   = (int*)(ws + 32768);            //     40,960 B (padded)
  int* offsets  = (int*)(ws + 73728);            //     40,960 B
  int* cursor   = (int*)(ws + 114688);           //     40,960 B
  float* aggW   = (float*)(ws + 155648);         //  5,120,000 B
  int4* triple  = (int4*)(ws + 5275648);         // 25,600,000 B
  // total: 30,875,648 B of d_ws

  apk0_prep<<<640, 256, 0, stream>>>(W1a, WTg, counts, aggW);
  apk2_hist<<<2048, 256, 0, stream>>>(dst, counts);
  apk3_scan<<<1, 256, 0, stream>>>(counts, offsets, cursor);
  apk4_scatter<<<2048, 256, 0, stream>>>(dst, src, cursor, triple);
  apk5_edges<<<N_E / 128, 256, 0, stream>>>(edge_hid, ue_hid, WTg, b1a, triple, aggW);
  apk6_mlp2<<<N_AP / 16, 256, 0, stream>>>(ap_hid, W1b, b1b, W2a, b2a, W2b, b2b,
                                           aggW, offsets, out);
}

// Round 3
// 914.258 us; speedup vs baseline: 1.0361x; 1.0361x over previous
//
#include <hip/hip_runtime.h>
#include <hip/hip_bf16.h>

// Problem constants (match reference)
#define N_UE 100000
#define N_AP 10000
#define N_E  1600000
#define DD   64
#define HH   128
#define NTILE (N_E / 128)   // 12500 fixed 128-edge tiles

typedef float f32x4 __attribute__((ext_vector_type(4)));
typedef short s8b   __attribute__((ext_vector_type(8)));
typedef short s4b   __attribute__((ext_vector_type(4)));

static __device__ __forceinline__ unsigned short f2bf(float x) {
  union { float f; unsigned int u; } v; v.f = x;
  unsigned int r = v.u + 0x7fffu + ((v.u >> 16) & 1u);  // RTN-even
  return (unsigned short)(r >> 16);
}

// K0: WTg[col][k] = bf16(W1a[k][col]) for full K=128 (B operand, [n][k]);
//     zero histogram counters and aggW accumulator.
__global__ void apk0_prep(const float* __restrict__ W1a, short* __restrict__ WTg,
                          int* __restrict__ counts, float* __restrict__ aggW) {
  int i = blockIdx.x * 256 + threadIdx.x;
  int n = gridDim.x * 256;
  for (int x = i; x < 128 * 128; x += n) {
    int col = x >> 7, k = x & 127;
    WTg[x] = (short)f2bf(W1a[k * 128 + col]);   // WTg[col*128 + k]
  }
  for (int x = i; x < N_AP; x += n) counts[x] = 0;
  for (int x = i; x < N_AP * 128 / 4; x += n)
    ((float4*)aggW)[x] = make_float4(0.f, 0.f, 0.f, 0.f);
}

// K2: histogram of dst
__global__ void apk2_hist(const int* __restrict__ dst, int* __restrict__ counts) {
  int i = blockIdx.x * blockDim.x + threadIdx.x;
  int stride = gridDim.x * blockDim.x;
  for (; i < N_E; i += stride) atomicAdd(&counts[dst[i]], 1);
}

// K3: exclusive scan of counts -> offsets[10001]; cursor = offsets copy
__global__ __launch_bounds__(256) void apk3_scan(const int* __restrict__ counts,
                                                 int* __restrict__ offsets,
                                                 int* __restrict__ cursor) {
  __shared__ int p[256];
  int t = threadIdx.x;
  const int CH = 40;  // 256*40 >= 10000
  int start = t * CH, end = min(start + CH, N_AP);
  int s = 0;
  for (int i = start; i < end; i++) s += counts[i];
  p[t] = s;
  __syncthreads();
  for (int d = 1; d < 256; d <<= 1) {
    int v = p[t] + ((t >= d) ? p[t - d] : 0);
    __syncthreads();
    p[t] = v;
    __syncthreads();
  }
  int base = (t == 0) ? 0 : p[t - 1];
  for (int i = start; i < end; i++) {
    offsets[i] = base;
    cursor[i] = base;
    base += counts[i];
  }
  if (t == 255) offsets[N_AP] = base;  // == N_E
}

// K4: scatter packed (edge_id, src, dst) into dst-sorted order, one int4/edge
__global__ void apk4_scatter(const int* __restrict__ dst, const int* __restrict__ src,
                             int* __restrict__ cursor, int4* __restrict__ triple) {
  int i = blockIdx.x * blockDim.x + threadIdx.x;
  int stride = gridDim.x * blockDim.x;
  for (; i < N_E; i += stride) {
    int d = dst[i];
    int pos = atomicAdd(&cursor[d], 1);
    triple[pos] = make_int4(i, src[i], d, 0);
  }
}

// K5: grid-stride over fixed 128-edge tiles of the dst-sorted edge list.
// A row p = [edge_hid[e_p] | ue_hid[src_p]] (bf16, K=128); B = W1a^T in VGPRs.
// C = A@W1a; t = relu(C + b1a); segment-reduce rows by dst (sorted) with
// per-quad register run-accumulators; cross-quad shfl + fp32 atomic flush
// only at AP boundaries.
__global__ __launch_bounds__(256, 4) void apk5_edges(
    const float* __restrict__ edge_hid, const float* __restrict__ ue_hid,
    const short* __restrict__ WTg, const float* __restrict__ b1a,
    const int4* __restrict__ triple, float* __restrict__ aggW) {
  __shared__ short A[128][132];    // A operand [edge][k] bf16, pitch 132
  __shared__ int segs[128];
  int t = threadIdx.x;
  int wave = t >> 6, lane = t & 63, quad = lane >> 4, l16 = lane & 15;

  // B fragments straight from global (16KB, L2-hot): wave owns cols [wave*32, +32)
  s8b bf[2][4];
  for (int ct = 0; ct < 2; ct++)
    for (int ks = 0; ks < 4; ks++)
      bf[ct][ks] = *(const s8b*)&WTg[(wave * 32 + ct * 16 + l16) * 128 +
                                     ks * 32 + quad * 8];
  float bias0 = b1a[wave * 32 + l16];
  float bias1 = b1a[wave * 32 + 16 + l16];

  int runseg = -1;
  float run0 = 0.f, run1 = 0.f;   // per-quad partials for current segment
  auto flush = [&]() {
    if (runseg >= 0) {
      float f0 = run0 + __shfl_xor(run0, 16); f0 += __shfl_xor(f0, 32);
      float f1 = run1 + __shfl_xor(run1, 16); f1 += __shfl_xor(f1, 32);
      if (quad == 0) {
        atomicAdd(&aggW[(size_t)runseg * 128 + wave * 32 + l16], f0);
        atomicAdd(&aggW[(size_t)runseg * 128 + wave * 32 + 16 + l16], f1);
      }
    }
  };

  const int r = t >> 1, h = t & 1;
  for (int tile = blockIdx.x; tile < NTILE; tile += gridDim.x) {
    int4 tr = triple[(size_t)tile * 128 + r];   // 2 threads share a row's triple
    __syncthreads();   // previous tile's LDS reads complete
    if (h == 0) segs[r] = tr.z;
    {
      const float* srow = h ? (ue_hid + (size_t)tr.y * 64)
                            : (edge_hid + (size_t)tr.x * 64);
      int kb = h * 64;
      #pragma unroll
      for (int cc = 0; cc < 8; cc++) {
        float4 v = ((const float4*)srow)[cc * 2];
        float4 w = ((const float4*)srow)[cc * 2 + 1];
        s8b p;
        p[0] = (short)f2bf(v.x); p[1] = (short)f2bf(v.y);
        p[2] = (short)f2bf(v.z); p[3] = (short)f2bf(v.w);
        p[4] = (short)f2bf(w.x); p[5] = (short)f2bf(w.y);
        p[6] = (short)f2bf(w.z); p[7] = (short)f2bf(w.w);
        *(s8b*)&A[r][kb + cc * 8] = p;
      }
    }
    __syncthreads();

    for (int rt = 0; rt < 8; rt++) {
      s8b a0 = *(const s8b*)&A[rt * 16 + l16][0 + quad * 8];
      s8b a1 = *(const s8b*)&A[rt * 16 + l16][32 + quad * 8];
      s8b a2 = *(const s8b*)&A[rt * 16 + l16][64 + quad * 8];
      s8b a3 = *(const s8b*)&A[rt * 16 + l16][96 + quad * 8];
      f32x4 c0 = {0.f, 0.f, 0.f, 0.f}, c1 = {0.f, 0.f, 0.f, 0.f};
      c0 = __builtin_amdgcn_mfma_f32_16x16x32_bf16(a0, bf[0][0], c0, 0, 0, 0);
      c0 = __builtin_amdgcn_mfma_f32_16x16x32_bf16(a1, bf[0][1], c0, 0, 0, 0);
      c0 = __builtin_amdgcn_mfma_f32_16x16x32_bf16(a2, bf[0][2], c0, 0, 0, 0);
      c0 = __builtin_amdgcn_mfma_f32_16x16x32_bf16(a3, bf[0][3], c0, 0, 0, 0);
      c1 = __builtin_amdgcn_mfma_f32_16x16x32_bf16(a0, bf[1][0], c1, 0, 0, 0);
      c1 = __builtin_amdgcn_mfma_f32_16x16x32_bf16(a1, bf[1][1], c1, 0, 0, 0);
      c1 = __builtin_amdgcn_mfma_f32_16x16x32_bf16(a2, bf[1][2], c1, 0, 0, 0);
      c1 = __builtin_amdgcn_mfma_f32_16x16x32_bf16(a3, bf[1][3], c1, 0, 0, 0);
      float t0[4], t1[4];
      #pragma unroll
      for (int j = 0; j < 4; j++) {
        t0[j] = fmaxf(c0[j] + bias0, 0.f);
        t1[j] = fmaxf(c1[j] + bias1, 0.f);
      }
      int gb = rt * 16;
      int sF = segs[gb], sL = segs[gb + 15];
      if (sF == sL) {                       // uniform group (common case)
        if (sF != runseg) { flush(); runseg = sF; run0 = 0.f; run1 = 0.f; }
        run0 += t0[0] + t0[1] + t0[2] + t0[3];
        run1 += t1[0] + t1[1] + t1[2] + t1[3];
      } else {                              // AP boundary inside group (rare)
        int sj[4];
        #pragma unroll
        for (int j = 0; j < 4; j++) sj[j] = segs[gb + quad * 4 + j];
        for (int s = sF; s <= sL; s++) {
          float v0 = 0.f, v1 = 0.f;
          #pragma unroll
          for (int j = 0; j < 4; j++)
            if (sj[j] == s) { v0 += t0[j]; v1 += t1[j]; }
          if (s == runseg) { run0 += v0; run1 += v1; }
          else { flush(); runseg = s; run0 = v0; run1 = v1; }
        }
      }
    }
  }
  flush();
}

// K6: per 16 APs: Y = aggW@W1b + cnt*b1b;  T = relu([ap_hid,Y]@W2a + b2a);
//     out = T@W2b + b2b.  All fp32, weights staged through a 32KB LDS buffer.
__global__ __launch_bounds__(256) void apk6_mlp2(
    const float* __restrict__ ap_hid, const float* __restrict__ W1b,
    const float* __restrict__ b1b, const float* __restrict__ W2a,
    const float* __restrict__ b2a, const float* __restrict__ W2b,
    const float* __restrict__ b2b, const float* __restrict__ aggW,
    const int* __restrict__ offsets, float* __restrict__ out) {
  __shared__ float wbuf[64 * 128];   // 32KB weight tile
  __shared__ float zrows[16 * 128];  // agg rows, later reused as T
  __shared__ float yrows[16 * 128];
  __shared__ float arows[16 * 64];
  __shared__ float cbuf[16];
  int t = threadIdx.x;
  int apb = blockIdx.x * 16;
  for (int i = t; i < 16 * 128 / 4; i += 256)
    ((float4*)zrows)[i] = ((const float4*)(aggW + (size_t)apb * 128))[i];
  for (int i = t; i < 16 * 64 / 4; i += 256)
    ((float4*)arows)[i] = ((const float4*)(ap_hid + (size_t)apb * 64))[i];
  if (t < 16) cbuf[t] = (float)(offsets[apb + t + 1] - offsets[apb + t]);
  int j = t & 127, half = t >> 7;
  // ---- phase 1: Y = agg @ W1b + cnt*b1b
  {
    float bb = b1b[j];
    __syncthreads();
    float acc[8];
    for (int r = 0; r < 8; r++) acc[r] = cbuf[half * 8 + r] * bb;
    for (int p = 0; p < 2; p++) {
      __syncthreads();
      for (int i = t; i < 64 * 128 / 4; i += 256)
        ((float4*)wbuf)[i] = ((const float4*)(W1b + p * 64 * 128))[i];
      __syncthreads();
      for (int k = 0; k < 64; k++) {
        float w = wbuf[k * 128 + j];
        for (int r = 0; r < 8; r++)
          acc[r] += zrows[(half * 8 + r) * 128 + (p * 64 + k)] * w;
      }
    }
    for (int r = 0; r < 8; r++) yrows[(half * 8 + r) * 128 + j] = acc[r];
  }
  // ---- phase 2: T = relu([ap, Y] @ W2a + b2a), stored into zrows
  {
    float acc2[8];
    float bb = b2a[j];
    for (int r = 0; r < 8; r++) acc2[r] = bb;
    __syncthreads();
    for (int i = t; i < 64 * 128 / 4; i += 256)
      ((float4*)wbuf)[i] = ((const float4*)W2a)[i];
    __syncthreads();
    for (int k = 0; k < 64; k++) {
      float w = wbuf[k * 128 + j];
      for (int r = 0; r < 8; r++) acc2[r] += arows[(half * 8 + r) * 64 + k] * w;
    }
    for (int p = 0; p < 2; p++) {
      __syncthreads();
      for (int i = t; i < 64 * 128 / 4; i += 256)
        ((float4*)wbuf)[i] = ((const float4*)(W2a + (64 + p * 64) * 128))[i];
      __syncthreads();
      for (int k = 0; k < 64; k++) {
        float w = wbuf[k * 128 + j];
        for (int r = 0; r < 8; r++)
          acc2[r] += yrows[(half * 8 + r) * 128 + (p * 64 + k)] * w;
      }
    }
    __syncthreads();
    for (int r = 0; r < 8; r++)
      zrows[(half * 8 + r) * 128 + j] = fmaxf(acc2[r], 0.f);
  }
  // ---- phase 3: out = T @ W2b + b2b
  {
    __syncthreads();
    for (int i = t; i < 128 * 64 / 4; i += 256)
      ((float4*)wbuf)[i] = ((const float4*)W2b)[i];
    __syncthreads();
    int i2 = t & 63, q = t >> 6;
    float acc3[4];
    float bb = b2b[i2];
    for (int r = 0; r < 4; r++) acc3[r] = bb;
    for (int k = 0; k < 128; k++) {
      float w = wbuf[k * 64 + i2];
      for (int r = 0; r < 4; r++) acc3[r] += zrows[(q * 4 + r) * 128 + k] * w;
    }
    for (int r = 0; r < 4; r++)
      out[(size_t)(apb + q * 4 + r) * 64 + i2] = acc3[r];
  }
}

extern "C" void kernel_launch(void* const* d_in, const int* in_sizes, int n_in,
                              void* d_out, int out_size, void* d_ws, size_t ws_size,
                              hipStream_t stream) {
  const float* ue_hid   = (const float*)d_in[0];
  const float* ap_hid   = (const float*)d_in[1];
  const float* edge_hid = (const float*)d_in[2];
  const int*   src      = (const int*)d_in[3];
  const int*   dst      = (const int*)d_in[4];
  const float* W1a      = (const float*)d_in[5];
  const float* b1a      = (const float*)d_in[6];
  const float* W1b      = (const float*)d_in[7];
  const float* b1b      = (const float*)d_in[8];
  const float* W2a      = (const float*)d_in[9];
  const float* b2a      = (const float*)d_in[10];
  const float* W2b      = (const float*)d_in[11];
  const float* b2b      = (const float*)d_in[12];
  float* out = (float*)d_out;

  unsigned char* ws = (unsigned char*)d_ws;
  short* WTg    = (short*)(ws);                  //     32,768 B
  int* counts   = (int*)(ws + 32768);            //     40,960 B (padded)
  int* offsets  = (int*)(ws + 73728);            //     40,960 B
  int* cursor   = (int*)(ws + 114688);           //     40,960 B
  float* aggW   = (float*)(ws + 155648);         //  5,120,000 B
  int4* triple  = (int4*)(ws + 5275648);         // 25,600,000 B
  // total: 30,875,648 B of d_ws

  apk0_prep<<<640, 256, 0, stream>>>(W1a, WTg, counts, aggW);
  apk2_hist<<<2048, 256, 0, stream>>>(dst, counts);
  apk3_scan<<<1, 256, 0, stream>>>(counts, offsets, cursor);
  apk4_scatter<<<2048, 256, 0, stream>>>(dst, src, cursor, triple);
  apk5_edges<<<2048, 256, 0, stream>>>(edge_hid, ue_hid, WTg, b1a, triple, aggW);
  apk6_mlp2<<<N_AP / 16, 256, 0, stream>>>(ap_hid, W1b, b1b, W2a, b2a, W2b, b2b,
                                           aggW, offsets, out);
}